// Round 1
// baseline (6835.829 us; speedup 1.0000x reference)
//
#include <hip/hip_runtime.h>
#include <hip/hip_bf16.h>

typedef __attribute__((ext_vector_type(8))) short short8;
typedef __attribute__((ext_vector_type(4))) float f32x4;

#define VOC 32000
#define EMB 512
#define HID 1024
#define BB  16
#define SS  256
#define NROW 4096   // S*B rows, ordered r = t*16 + b

__device__ __forceinline__ unsigned short f2bf(float f) {
    unsigned int u = __float_as_uint(f);
    unsigned int r = (u + 0x7fffu + ((u >> 16) & 1u)) >> 16;
    return (unsigned short)r;
}
__device__ __forceinline__ float bf2f(unsigned short s) {
    return __uint_as_float(((unsigned int)s) << 16);
}
__device__ __forceinline__ float sigf(float x) {
    return 1.f / (1.f + __expf(-x));
}
__device__ __forceinline__ float tanh_c(float x) {
    x = fminf(fmaxf(x, -15.f), 15.f);
    float e = __expf(2.f * x);
    return (e - 1.f) / (e + 1.f);
}

// ---------------- utility kernels ----------------
__global__ void k_zero(float* p, int n) {
    int i = blockIdx.x * blockDim.x + threadIdx.x;
    int st = gridDim.x * blockDim.x;
    for (; i < n; i += st) p[i] = 0.f;
}

__global__ void k_f32_to_bf16(const float* __restrict__ src,
                              unsigned short* __restrict__ dst, int n4) {
    int i = blockIdx.x * blockDim.x + threadIdx.x;
    int st = gridDim.x * blockDim.x;
    for (; i < n4; i += st) {
        float4 v = ((const float4*)src)[i];
        ushort4 o;
        o.x = f2bf(v.x); o.y = f2bf(v.y); o.z = f2bf(v.z); o.w = f2bf(v.w);
        ((ushort4*)dst)[i] = o;
    }
}

__global__ void k_bias(const float* bi1, const float* bh1,
                       const float* bi2, const float* bh2,
                       float* b1, float* b2) {
    int i = blockIdx.x * blockDim.x + threadIdx.x;
    if (i < 4 * HID) { b1[i] = bi1[i] + bh1[i]; b2[i] = bi2[i] + bh2[i]; }
}

// gather embedding rows -> bf16 A [4096][512], row r = t*16+b
__global__ void k_embed(const int* __restrict__ tok, const float* __restrict__ emb,
                        unsigned short* __restrict__ A) {
    int idx = blockIdx.x * 256 + threadIdx.x;   // float4 chunk id, 4096*128 total
    if (idx >= NROW * (EMB / 4)) return;
    int r = idx >> 7, c4 = idx & 127;
    int t = r >> 4, b = r & 15;
    int token = tok[b * SS + t];
    float4 v = ((const float4*)(emb + (size_t)token * EMB))[c4];
    ushort4 o;
    o.x = f2bf(v.x); o.y = f2bf(v.y); o.z = f2bf(v.z); o.w = f2bf(v.w);
    ((ushort4*)(A + (size_t)r * EMB))[c4] = o;
}

// ---------------- bf16 MFMA GEMM: C[M,N] = A[M,K] @ B[N,K]^T + bias[N] ----------------
// 128x128 tile, BK=32, 4 waves in 2x2, 4x4 fragments of 16x16x32 each.
__global__ __launch_bounds__(256) void k_gemm_bt(
    const unsigned short* __restrict__ A, const unsigned short* __restrict__ B,
    const float* __restrict__ bias, float* __restrict__ C,
    int M, int N, int K, int scatter) {
    __shared__ __align__(16) unsigned short As[128 * 32];
    __shared__ __align__(16) unsigned short Bs[128 * 32];
    int tid = threadIdx.x;
    int wave = tid >> 6, lane = tid & 63;
    int bRow = blockIdx.y * 128, bCol = blockIdx.x * 128;
    int wr = (wave >> 1) * 64, wc = (wave & 1) * 64;
    f32x4 acc[4][4] = {};

    int lrow = lane & 15, khalf = (lane >> 4) * 8;

    for (int kt = 0; kt < K; kt += 32) {
#pragma unroll
        for (int q = 0; q < 2; ++q) {
            int chunk = tid + 256 * q;            // 0..511
            int row = chunk >> 2, c8 = (chunk & 3) * 8;
            short8 va = *(const short8*)(A + (size_t)(bRow + row) * K + kt + c8);
            *(short8*)(&As[row * 32 + c8]) = va;
            short8 vb = *(const short8*)(B + (size_t)(bCol + row) * K + kt + c8);
            *(short8*)(&Bs[row * 32 + c8]) = vb;
        }
        __syncthreads();
        short8 a[4], b[4];
#pragma unroll
        for (int i = 0; i < 4; ++i)
            a[i] = *(const short8*)(&As[(wr + 16 * i + lrow) * 32 + khalf]);
#pragma unroll
        for (int j = 0; j < 4; ++j)
            b[j] = *(const short8*)(&Bs[(wc + 16 * j + lrow) * 32 + khalf]);
#pragma unroll
        for (int i = 0; i < 4; ++i)
#pragma unroll
            for (int j = 0; j < 4; ++j)
                acc[i][j] = __builtin_amdgcn_mfma_f32_16x16x32_bf16(a[i], b[j], acc[i][j], 0, 0, 0);
        __syncthreads();
    }

    int lcol = lane & 15, lrow4 = (lane >> 4) * 4;
#pragma unroll
    for (int i = 0; i < 4; ++i)
#pragma unroll
        for (int j = 0; j < 4; ++j)
#pragma unroll
            for (int q = 0; q < 4; ++q) {
                int gr = bRow + wr + 16 * i + lrow4 + q;
                int gc = bCol + wc + 16 * j + lcol;
                float v = acc[i][j][q] + bias[gc];
                size_t orow = scatter ? (size_t)(((gr & 15) << 8) | (gr >> 4)) : (size_t)gr;
                C[orow * (size_t)N + gc] = v;
            }
}

// ---------------- per-timestep LSTM cell kernel ----------------
// gates[b][gcol] = X[(t*16+b)][gcol] + sum_k h_old[b][k] * Whh[gcol][k]
// block owns 4 h-columns (hc = 4*blockIdx.x + hcl), all 4 gate types, all 16 batch.
__global__ __launch_bounds__(256) void k_step(
    const float* __restrict__ X,            // [4096][4096] incl. both biases
    const unsigned short* __restrict__ Whh, // [4096][1024] bf16
    const float* __restrict__ h_old,        // [16][1024]
    float* __restrict__ h_new,              // [16][1024]
    float* __restrict__ c,                  // [16][1024] in-place
    unsigned short* __restrict__ h_seq,     // [4096][1024] bf16, row t*16+b
    int t) {
    __shared__ __align__(16) float hs[16][1028];  // stride 1028: 16B aligned, 2-way banks
    __shared__ float gs[16][17];
    int tid = threadIdx.x;
#pragma unroll
    for (int i = 0; i < 16; ++i) {
        int e4 = tid + 256 * i;             // float4 id over 16*1024
        int b2 = e4 >> 8, k4 = e4 & 255;
        float4 v = ((const float4*)h_old)[e4];
        *(float4*)(&hs[b2][k4 * 4]) = v;
    }
    __syncthreads();

    int b = tid & 15, idx = tid >> 4;
    int typ = idx >> 2, hcl = idx & 3;
    int gcol = typ * HID + blockIdx.x * 4 + hcl;
    float acc = X[(size_t)(t * 16 + b) * 4096 + gcol];
    const unsigned short* wrow = Whh + (size_t)gcol * HID;
#pragma unroll 4
    for (int k8 = 0; k8 < HID / 8; ++k8) {
        short8 w = ((const short8*)wrow)[k8];
        float4 h0 = *(const float4*)(&hs[b][k8 * 8]);
        float4 h1 = *(const float4*)(&hs[b][k8 * 8 + 4]);
        acc += h0.x * bf2f((unsigned short)w[0]);
        acc += h0.y * bf2f((unsigned short)w[1]);
        acc += h0.z * bf2f((unsigned short)w[2]);
        acc += h0.w * bf2f((unsigned short)w[3]);
        acc += h1.x * bf2f((unsigned short)w[4]);
        acc += h1.y * bf2f((unsigned short)w[5]);
        acc += h1.z * bf2f((unsigned short)w[6]);
        acc += h1.w * bf2f((unsigned short)w[7]);
    }
    gs[idx][b] = acc;
    __syncthreads();

    if (tid < 64) {
        int bb = tid & 15, hl = tid >> 4;
        int col = blockIdx.x * 4 + hl;
        float gi = gs[0 + hl][bb];
        float gf = gs[4 + hl][bb];
        float gg = gs[8 + hl][bb];
        float go = gs[12 + hl][bb];
        float cold = c[bb * HID + col];
        float cn = sigf(gf) * cold + sigf(gi) * tanh_c(gg);
        float hn = sigf(go) * tanh_c(cn);
        c[bb * HID + col] = cn;
        h_new[bb * HID + col] = hn;
        h_seq[(size_t)(t * 16 + bb) * HID + col] = f2bf(hn);
    }
}

// ---------------- log-softmax ----------------
__global__ __launch_bounds__(256) void k_lse(const float* __restrict__ logits,
                                             float* __restrict__ lse) {
    int r = blockIdx.x;
    const float* row = logits + (size_t)r * VOC;
    int tid = threadIdx.x;
    float m = -3.4e38f, s = 0.f;
    for (int i = 0; i < VOC / 256; ++i) {
        float x = row[tid + 256 * i];
        float mn = fmaxf(m, x);
        s = s * __expf(m - mn) + __expf(x - mn);
        m = mn;
    }
#pragma unroll
    for (int off = 1; off < 64; off <<= 1) {
        float m2 = __shfl_xor(m, off);
        float s2 = __shfl_xor(s, off);
        float mn = fmaxf(m, m2);
        s = s * __expf(m - mn) + s2 * __expf(m2 - mn);
        m = mn;
    }
    __shared__ float sm[4], ss_[4];
    int w = tid >> 6;
    if ((tid & 63) == 0) { sm[w] = m; ss_[w] = s; }
    __syncthreads();
    if (tid == 0) {
        m = sm[0]; s = ss_[0];
        for (int i = 1; i < 4; ++i) {
            float mn = fmaxf(m, sm[i]);
            s = s * __expf(m - mn) + ss_[i] * __expf(sm[i] - mn);
            m = mn;
        }
        lse[r] = m + __logf(s);
    }
}

__global__ void k_sub(float* __restrict__ logits, const float* __restrict__ lse) {
    int r = blockIdx.y;
    int i4 = blockIdx.x * 256 + threadIdx.x;
    if (i4 >= VOC / 4) return;
    float l = lse[r];
    float4* p = (float4*)(logits + (size_t)r * VOC) + i4;
    float4 v = *p;
    v.x -= l; v.y -= l; v.z -= l; v.w -= l;
    *p = v;
}

// ---------------- launch ----------------
extern "C" void kernel_launch(void* const* d_in, const int* in_sizes, int n_in,
                              void* d_out, int out_size, void* d_ws, size_t ws_size,
                              hipStream_t stream) {
    const int*   tok   = (const int*)d_in[0];
    const float* emb   = (const float*)d_in[1];
    const float* W_ih1 = (const float*)d_in[2];
    const float* W_hh1 = (const float*)d_in[3];
    const float* b_ih1 = (const float*)d_in[4];
    const float* b_hh1 = (const float*)d_in[5];
    const float* W_ih2 = (const float*)d_in[6];
    const float* W_hh2 = (const float*)d_in[7];
    const float* b_ih2 = (const float*)d_in[8];
    const float* b_hh2 = (const float*)d_in[9];
    const float* W_log = (const float*)d_in[10];
    const float* b_log = (const float*)d_in[11];
    float* out = (float*)d_out;

    char* w = (char*)d_ws;
    auto alloc = [&](size_t bytes) {
        char* p = w;
        w += (bytes + 255) & ~(size_t)255;
        return p;
    };
    unsigned short* Wih1b = (unsigned short*)alloc((size_t)4096 * 512 * 2);
    unsigned short* Whh1b = (unsigned short*)alloc((size_t)4096 * 1024 * 2);
    unsigned short* Wih2b = (unsigned short*)alloc((size_t)4096 * 1024 * 2);
    unsigned short* Whh2b = (unsigned short*)alloc((size_t)4096 * 1024 * 2);
    unsigned short* Wlogb = (unsigned short*)alloc((size_t)VOC * 1024 * 2);
    unsigned short* Abuf  = (unsigned short*)alloc((size_t)4096 * 512 * 2);
    float* X              = (float*)alloc((size_t)4096 * 4096 * 4);
    unsigned short* h1seq = (unsigned short*)alloc((size_t)4096 * 1024 * 2);
    unsigned short* h2seq = (unsigned short*)alloc((size_t)4096 * 1024 * 2);
    float* b1s            = (float*)alloc(4096 * 4);
    float* b2s            = (float*)alloc(4096 * 4);
    float* state          = (float*)alloc((size_t)6 * 16 * 1024 * 4);
    float* lse            = (float*)alloc(4096 * 4);
    float* h1a = state,                 *h1b = state + 16 * 1024, *c1 = state + 2 * 16 * 1024;
    float* h2a = state + 3 * 16 * 1024, *h2b = state + 4 * 16 * 1024, *c2 = state + 5 * 16 * 1024;

    // zero recurrent state every call (graph replays must be self-initializing)
    k_zero<<<96, 256, 0, stream>>>(state, 6 * 16 * 1024);

    // weight conversions (idempotent)
    k_f32_to_bf16<<<2048, 256, 0, stream>>>(W_ih1, Wih1b, 4096 * 512 / 4);
    k_f32_to_bf16<<<2048, 256, 0, stream>>>(W_hh1, Whh1b, 4096 * 1024 / 4);
    k_f32_to_bf16<<<2048, 256, 0, stream>>>(W_ih2, Wih2b, 4096 * 1024 / 4);
    k_f32_to_bf16<<<2048, 256, 0, stream>>>(W_hh2, Whh2b, 4096 * 1024 / 4);
    k_f32_to_bf16<<<2048, 256, 0, stream>>>(W_log, Wlogb, VOC * 1024 / 4);
    k_bias<<<16, 256, 0, stream>>>(b_ih1, b_hh1, b_ih2, b_hh2, b1s, b2s);

    // X1 = embed @ W_ih1^T + (b_ih1 + b_hh1)
    k_embed<<<2048, 256, 0, stream>>>(tok, emb, Abuf);
    k_gemm_bt<<<dim3(32, 32), 256, 0, stream>>>(Abuf, Wih1b, b1s, X, 4096, 4096, 512, 0);

    // layer 1 recurrence
    for (int t = 0; t < SS; ++t) {
        const float* ho = (t & 1) ? h1b : h1a;
        float* hn       = (t & 1) ? h1a : h1b;
        k_step<<<256, 256, 0, stream>>>(X, Whh1b, ho, hn, c1, h1seq, t);
    }

    // X2 = h1_seq @ W_ih2^T + (b_ih2 + b_hh2)
    k_gemm_bt<<<dim3(32, 32), 256, 0, stream>>>(h1seq, Wih2b, b2s, X, 4096, 4096, 1024, 0);

    // layer 2 recurrence
    for (int t = 0; t < SS; ++t) {
        const float* ho = (t & 1) ? h2b : h2a;
        float* hn       = (t & 1) ? h2a : h2b;
        k_step<<<256, 256, 0, stream>>>(X, Whh2b, ho, hn, c2, h2seq, t);
    }

    // logits = h2_seq @ W_log^T + b_log, scattered to [b][t][v]
    k_gemm_bt<<<dim3(VOC / 128, 32), 256, 0, stream>>>(h2seq, Wlogb, b_log, out,
                                                       4096, VOC, 1024, 1);

    // log-softmax in place
    k_lse<<<4096, 256, 0, stream>>>(out, lse);
    k_sub<<<dim3(32, 4096), 256, 0, stream>>>(out, lse);
}

// Round 2
// 5881.187 us; speedup vs baseline: 1.1623x; 1.1623x over previous
//
#include <hip/hip_runtime.h>
#include <hip/hip_bf16.h>

typedef __attribute__((ext_vector_type(8))) _Float16 half8;
typedef __attribute__((ext_vector_type(4))) _Float16 half4;
typedef __attribute__((ext_vector_type(4))) float f32x4;

#define VOC 32000
#define EMB 512
#define HID 1024
#define SS  256
#define NROW 4096   // S*B rows, ordered r = t*16 + b
#define RBLK 64     // persistent recurrence blocks

__device__ __forceinline__ float sigf(float x) {
    return 1.f / (1.f + __expf(-x));
}
__device__ __forceinline__ float tanh_c(float x) {
    x = fminf(fmaxf(x, -15.f), 15.f);
    float e = __expf(2.f * x);
    return (e - 1.f) / (e + 1.f);
}

// ---------------- utility kernels ----------------
__global__ void k_zero(float* p, int n) {
    int i = blockIdx.x * blockDim.x + threadIdx.x;
    int st = gridDim.x * blockDim.x;
    for (; i < n; i += st) p[i] = 0.f;
}

__global__ void k_f32_to_f16(const float* __restrict__ src,
                             _Float16* __restrict__ dst, int n4) {
    int i = blockIdx.x * blockDim.x + threadIdx.x;
    int st = gridDim.x * blockDim.x;
    for (; i < n4; i += st) {
        float4 v = ((const float4*)src)[i];
        half4 o = {(_Float16)v.x, (_Float16)v.y, (_Float16)v.z, (_Float16)v.w};
        ((half4*)dst)[i] = o;
    }
}

__global__ void k_bias(const float* bi1, const float* bh1,
                       const float* bi2, const float* bh2,
                       float* b1, float* b2) {
    int i = blockIdx.x * blockDim.x + threadIdx.x;
    if (i < 4 * HID) { b1[i] = bi1[i] + bh1[i]; b2[i] = bi2[i] + bh2[i]; }
}

// gather embedding rows -> f16 A [4096][512], row r = t*16+b
__global__ void k_embed(const int* __restrict__ tok, const float* __restrict__ emb,
                        _Float16* __restrict__ A) {
    int idx = blockIdx.x * 256 + threadIdx.x;   // float4 chunk id
    if (idx >= NROW * (EMB / 4)) return;
    int r = idx >> 7, c4 = idx & 127;
    int t = r >> 4, b = r & 15;
    int token = tok[b * SS + t];
    float4 v = ((const float4*)(emb + (size_t)token * EMB))[c4];
    half4 o = {(_Float16)v.x, (_Float16)v.y, (_Float16)v.z, (_Float16)v.w};
    ((half4*)(A + (size_t)r * EMB))[c4] = o;
}

// ---------------- f16 MFMA GEMM: C[M,N] = A[M,K] @ B[N,K]^T + bias[N] ----------------
__global__ __launch_bounds__(256) void k_gemm_bt(
    const _Float16* __restrict__ A, const _Float16* __restrict__ B,
    const float* __restrict__ bias, float* __restrict__ C,
    int M, int N, int K, int scatter) {
    __shared__ __align__(16) _Float16 As[128 * 32];
    __shared__ __align__(16) _Float16 Bs[128 * 32];
    int tid = threadIdx.x;
    int wave = tid >> 6, lane = tid & 63;
    int bRow = blockIdx.y * 128, bCol = blockIdx.x * 128;
    int wr = (wave >> 1) * 64, wc = (wave & 1) * 64;
    f32x4 acc[4][4] = {};

    int lrow = lane & 15, khalf = (lane >> 4) * 8;

    for (int kt = 0; kt < K; kt += 32) {
#pragma unroll
        for (int q = 0; q < 2; ++q) {
            int chunk = tid + 256 * q;
            int row = chunk >> 2, c8 = (chunk & 3) * 8;
            half8 va = *(const half8*)(A + (size_t)(bRow + row) * K + kt + c8);
            *(half8*)(&As[row * 32 + c8]) = va;
            half8 vb = *(const half8*)(B + (size_t)(bCol + row) * K + kt + c8);
            *(half8*)(&Bs[row * 32 + c8]) = vb;
        }
        __syncthreads();
        half8 a[4], b[4];
#pragma unroll
        for (int i = 0; i < 4; ++i)
            a[i] = *(const half8*)(&As[(wr + 16 * i + lrow) * 32 + khalf]);
#pragma unroll
        for (int j = 0; j < 4; ++j)
            b[j] = *(const half8*)(&Bs[(wc + 16 * j + lrow) * 32 + khalf]);
#pragma unroll
        for (int i = 0; i < 4; ++i)
#pragma unroll
            for (int j = 0; j < 4; ++j)
                acc[i][j] = __builtin_amdgcn_mfma_f32_16x16x32_f16(a[i], b[j], acc[i][j], 0, 0, 0);
        __syncthreads();
    }

    int lcol = lane & 15, lrow4 = (lane >> 4) * 4;
#pragma unroll
    for (int i = 0; i < 4; ++i)
#pragma unroll
        for (int j = 0; j < 4; ++j)
#pragma unroll
            for (int q = 0; q < 4; ++q) {
                int gr = bRow + wr + 16 * i + lrow4 + q;
                int gc = bCol + wc + 16 * j + lcol;
                float v = acc[i][j][q] + bias[gc];
                size_t orow = scatter ? (size_t)(((gr & 15) << 8) | (gr >> 4)) : (size_t)gr;
                C[orow * (size_t)N + gc] = v;
            }
}

// ---------------- persistent LSTM layer kernel ----------------
// 64 blocks x 256 threads, all co-resident (<=256 CUs). Block bid owns h-cols
// [bid*16, bid*16+16). Wave w = gate w (i,f,g,o). W_hh slice lives in VGPRs
// (32 x half8 per lane). h ping-pong in global, fragment layout
// hbuf[buf][kt][batch][ko] (kt = k/32, ko = k%32), f16.
__global__ __launch_bounds__(256, 1) void k_lstm(
    const float* __restrict__ X,             // [4096][4096] f32: x@Wih^T + both biases
    const _Float16* __restrict__ Whh,        // [4096][1024] f16 row-major
    _Float16* __restrict__ hbuf,             // [2][16384] halves (frag layout)
    _Float16* __restrict__ hseq,             // [4096][1024] f16 row-major out
    unsigned* __restrict__ cnt) {
    __shared__ float gs[4][1024];
    int tid = threadIdx.x;
    int w = tid >> 6, l = tid & 63;
    int bid = blockIdx.x;

    // ---- weight preload into VGPRs (one-time) ----
    half8 wf[32];
    {
        const _Float16* wp = Whh + ((size_t)(w * HID + bid * 16 + (l & 15))) * HID + (l >> 4) * 8;
#pragma unroll
        for (int kt = 0; kt < 32; ++kt)
            wf[kt] = *(const half8*)(wp + kt * 32);
    }

    // elementwise ownership: thread tid -> (b = tid>>4, col = tid&15)
    int eb = tid >> 4, ecol = tid & 15;
    int gidx = ((eb >> 2) * 16 + ecol) * 4 + (eb & 3);
    int cg = bid * 16 + ecol;                       // global h column
    int hfrag_idx = ((cg >> 5) * 16 + eb) * 32 + (cg & 31);
    float creg = 0.f;

    const float* xbase = X + (size_t)w * HID + bid * 16 + (l & 15);
    const _Float16* habase0 = hbuf + (l & 15) * 32 + (l >> 4) * 8;

#pragma unroll 1
    for (int t = 0; t < SS; ++t) {
        // ---- X init for accumulator chain 0 ----
        int bq = (l >> 4) * 4;
        const float* xp = xbase + (size_t)(t * 16 + bq) * 4096;
        f32x4 a0, a1 = {}, a2 = {}, a3 = {};
        a0[0] = xp[0];
        a0[1] = xp[4096];
        a0[2] = xp[8192];
        a0[3] = xp[12288];

        // ---- h fragment loads (full h, 32 k-tiles) ----
        const _Float16* hb = habase0 + (t & 1) * 16384;
        half8 ha[32];
#pragma unroll
        for (int kt = 0; kt < 32; ++kt)
            ha[kt] = *(const half8*)(hb + kt * 512);

        // ---- 32 MFMAs, 4 independent K-chains ----
#pragma unroll
        for (int i = 0; i < 8; ++i) {
            a0 = __builtin_amdgcn_mfma_f32_16x16x32_f16(ha[i],      wf[i],      a0, 0, 0, 0);
            a1 = __builtin_amdgcn_mfma_f32_16x16x32_f16(ha[8 + i],  wf[8 + i],  a1, 0, 0, 0);
            a2 = __builtin_amdgcn_mfma_f32_16x16x32_f16(ha[16 + i], wf[16 + i], a2, 0, 0, 0);
            a3 = __builtin_amdgcn_mfma_f32_16x16x32_f16(ha[24 + i], wf[24 + i], a3, 0, 0, 0);
        }
        a0 = (a0 + a1) + (a2 + a3);

        // ---- gate exchange via LDS ----
        *(f32x4*)(&gs[w][l * 4]) = a0;
        __syncthreads();

        // ---- elementwise LSTM cell (all 256 threads, one (b,col) each) ----
        float gi = gs[0][gidx], gf = gs[1][gidx], gg = gs[2][gidx], go = gs[3][gidx];
        float cn = sigf(gf) * creg + sigf(gi) * tanh_c(gg);
        float hn = sigf(go) * tanh_c(cn);
        creg = cn;
        _Float16 hh = (_Float16)hn;
        hbuf[((t + 1) & 1) * 16384 + hfrag_idx] = hh;
        hseq[(size_t)(t * 16 + eb) * HID + cg] = hh;

        // ---- grid barrier (release h writes, protect gs WAR) ----
        if (t < SS - 1) {
            __syncthreads();
            if (tid == 0) {
                __threadfence();
                atomicAdd(cnt, 1u);
                unsigned tgt = (unsigned)RBLK * (unsigned)(t + 1);
                while (__hip_atomic_load(cnt, __ATOMIC_ACQUIRE, __HIP_MEMORY_SCOPE_AGENT) < tgt)
                    __builtin_amdgcn_s_sleep(4);
            }
            __syncthreads();
            __threadfence();   // acquire in all threads: invalidate L1 before h reads
        }
    }
}

// ---------------- log-softmax ----------------
__global__ __launch_bounds__(256) void k_lse(const float* __restrict__ logits,
                                             float* __restrict__ lse) {
    int r = blockIdx.x;
    const float* row = logits + (size_t)r * VOC;
    int tid = threadIdx.x;
    float m = -3.4e38f, s = 0.f;
    for (int i = 0; i < VOC / 256; ++i) {
        float x = row[tid + 256 * i];
        float mn = fmaxf(m, x);
        s = s * __expf(m - mn) + __expf(x - mn);
        m = mn;
    }
#pragma unroll
    for (int off = 1; off < 64; off <<= 1) {
        float m2 = __shfl_xor(m, off);
        float s2 = __shfl_xor(s, off);
        float mn = fmaxf(m, m2);
        s = s * __expf(m - mn) + s2 * __expf(m2 - mn);
        m = mn;
    }
    __shared__ float sm[4], ss_[4];
    int wv = tid >> 6;
    if ((tid & 63) == 0) { sm[wv] = m; ss_[wv] = s; }
    __syncthreads();
    if (tid == 0) {
        m = sm[0]; s = ss_[0];
        for (int i = 1; i < 4; ++i) {
            float mn = fmaxf(m, sm[i]);
            s = s * __expf(m - mn) + ss_[i] * __expf(sm[i] - mn);
            m = mn;
        }
        lse[r] = m + __logf(s);
    }
}

__global__ void k_sub(float* __restrict__ logits, const float* __restrict__ lse) {
    int r = blockIdx.y;
    int i4 = blockIdx.x * 256 + threadIdx.x;
    if (i4 >= VOC / 4) return;
    float l = lse[r];
    float4* p = (float4*)(logits + (size_t)r * VOC) + i4;
    float4 v = *p;
    v.x -= l; v.y -= l; v.z -= l; v.w -= l;
    *p = v;
}

// ---------------- launch ----------------
extern "C" void kernel_launch(void* const* d_in, const int* in_sizes, int n_in,
                              void* d_out, int out_size, void* d_ws, size_t ws_size,
                              hipStream_t stream) {
    const int*   tok   = (const int*)d_in[0];
    const float* emb   = (const float*)d_in[1];
    const float* W_ih1 = (const float*)d_in[2];
    const float* W_hh1 = (const float*)d_in[3];
    const float* b_ih1 = (const float*)d_in[4];
    const float* b_hh1 = (const float*)d_in[5];
    const float* W_ih2 = (const float*)d_in[6];
    const float* W_hh2 = (const float*)d_in[7];
    const float* b_ih2 = (const float*)d_in[8];
    const float* b_hh2 = (const float*)d_in[9];
    const float* W_log = (const float*)d_in[10];
    const float* b_log = (const float*)d_in[11];
    float* out = (float*)d_out;

    char* w = (char*)d_ws;
    auto alloc = [&](size_t bytes) {
        char* p = w;
        w += (bytes + 255) & ~(size_t)255;
        return p;
    };
    _Float16* Wih1h = (_Float16*)alloc((size_t)4096 * 512 * 2);
    _Float16* Whh1h = (_Float16*)alloc((size_t)4096 * 1024 * 2);
    _Float16* Wih2h = (_Float16*)alloc((size_t)4096 * 1024 * 2);
    _Float16* Whh2h = (_Float16*)alloc((size_t)4096 * 1024 * 2);
    _Float16* Wlogh = (_Float16*)alloc((size_t)VOC * 1024 * 2);
    _Float16* Abuf  = (_Float16*)alloc((size_t)4096 * 512 * 2);
    float* X        = (float*)alloc((size_t)4096 * 4096 * 4);
    _Float16* h1seq = (_Float16*)alloc((size_t)4096 * 1024 * 2);
    _Float16* h2seq = (_Float16*)alloc((size_t)4096 * 1024 * 2);
    float* b1s      = (float*)alloc(4096 * 4);
    float* b2s      = (float*)alloc(4096 * 4);
    _Float16* hbuf  = (_Float16*)alloc((size_t)2 * 16384 * 2);  // 64 KB ping-pong
    unsigned* cnts  = (unsigned*)alloc(256);                     // cnt1, cnt2
    float* lse      = (float*)alloc(4096 * 4);

    // zero h ping-pong + barrier counters (every launch: graph-replay safe)
    k_zero<<<32, 256, 0, stream>>>((float*)hbuf, 16384 + 64);

    // weight conversions f32 -> f16 (idempotent)
    k_f32_to_f16<<<2048, 256, 0, stream>>>(W_ih1, Wih1h, 4096 * 512 / 4);
    k_f32_to_f16<<<2048, 256, 0, stream>>>(W_hh1, Whh1h, 4096 * 1024 / 4);
    k_f32_to_f16<<<2048, 256, 0, stream>>>(W_ih2, Wih2h, 4096 * 1024 / 4);
    k_f32_to_f16<<<2048, 256, 0, stream>>>(W_hh2, Whh2h, 4096 * 1024 / 4);
    k_f32_to_f16<<<2048, 256, 0, stream>>>(W_log, Wlogh, VOC * 1024 / 4);
    k_bias<<<16, 256, 0, stream>>>(b_ih1, b_hh1, b_ih2, b_hh2, b1s, b2s);

    // X1 = embed @ W_ih1^T + (b_ih1 + b_hh1)
    k_embed<<<2048, 256, 0, stream>>>(tok, emb, Abuf);
    k_gemm_bt<<<dim3(32, 32), 256, 0, stream>>>(Abuf, Wih1h, b1s, X, 4096, 4096, 512, 0);

    // layer 1 recurrence (persistent, 64 blocks)
    k_lstm<<<RBLK, 256, 0, stream>>>(X, Whh1h, hbuf, h1seq, cnts);

    // re-zero h ping-pong for layer 2
    k_zero<<<32, 256, 0, stream>>>((float*)hbuf, 16384);

    // X2 = h1_seq @ W_ih2^T + (b_ih2 + b_hh2)
    k_gemm_bt<<<dim3(32, 32), 256, 0, stream>>>(h1seq, Wih2h, b2s, X, 4096, 4096, 1024, 0);

    // layer 2 recurrence
    k_lstm<<<RBLK, 256, 0, stream>>>(X, Whh2h, hbuf, h2seq, cnts + 16);

    // logits = h2_seq @ W_log^T + b_log, scattered to [b][t][v]
    k_gemm_bt<<<dim3(VOC / 128, 32), 256, 0, stream>>>(h2seq, Wlogh, b_log, out,
                                                       4096, VOC, 1024, 1);

    // log-softmax in place
    k_lse<<<4096, 256, 0, stream>>>(out, lse);
    k_sub<<<dim3(32, 4096), 256, 0, stream>>>(out, lse);
}

// Round 3
// 2496.718 us; speedup vs baseline: 2.7379x; 2.3556x over previous
//
#include <hip/hip_runtime.h>
#include <hip/hip_bf16.h>

typedef __attribute__((ext_vector_type(8))) _Float16 half8;
typedef __attribute__((ext_vector_type(4))) _Float16 half4;
typedef __attribute__((ext_vector_type(4))) float f32x4;

#define VOC 32000
#define EMB 512
#define HID 1024
#define SS  256
#define NROW 4096   // S*B rows, ordered r = t*16 + b
#define RBLK 64     // persistent recurrence blocks

__device__ __forceinline__ float sigf(float x) {
    return 1.f / (1.f + __expf(-x));
}
__device__ __forceinline__ float tanh_c(float x) {
    x = fminf(fmaxf(x, -15.f), 15.f);
    float e = __expf(2.f * x);
    return (e - 1.f) / (e + 1.f);
}

// ---- MALL-coherent (bypass L1+L2) primitives for cross-block traffic ----
__device__ __forceinline__ half8 ldg_h8_cc(const _Float16* p) {
    half8 r;
    asm volatile("global_load_dwordx4 %0, %1, off sc0 sc1" : "=v"(r) : "v"(p));
    return r;
}
__device__ __forceinline__ void stg_u16_cc(_Float16* p, unsigned short v) {
    asm volatile("global_store_short %0, %1, off sc0 sc1" :: "v"(p), "v"(v));
}
__device__ __forceinline__ void stg_u32_cc(unsigned* p, unsigned v) {
    asm volatile("global_store_dword %0, %1, off sc0 sc1" :: "v"(p), "v"(v) : "memory");
}
__device__ __forceinline__ unsigned ldg_u32_cc(const unsigned* p) {
    unsigned v;
    asm volatile("global_load_dword %0, %1, off sc0 sc1\n\ts_waitcnt vmcnt(0)"
                 : "=v"(v) : "v"(p) : "memory");
    return v;
}

// ---------------- utility kernels ----------------
__global__ void k_zero(float* p, int n) {
    int i = blockIdx.x * blockDim.x + threadIdx.x;
    int st = gridDim.x * blockDim.x;
    for (; i < n; i += st) p[i] = 0.f;
}

__global__ void k_f32_to_f16(const float* __restrict__ src,
                             _Float16* __restrict__ dst, int n4) {
    int i = blockIdx.x * blockDim.x + threadIdx.x;
    int st = gridDim.x * blockDim.x;
    for (; i < n4; i += st) {
        float4 v = ((const float4*)src)[i];
        half4 o = {(_Float16)v.x, (_Float16)v.y, (_Float16)v.z, (_Float16)v.w};
        ((half4*)dst)[i] = o;
    }
}

__global__ void k_bias(const float* bi1, const float* bh1,
                       const float* bi2, const float* bh2,
                       float* b1, float* b2) {
    int i = blockIdx.x * blockDim.x + threadIdx.x;
    if (i < 4 * HID) { b1[i] = bi1[i] + bh1[i]; b2[i] = bi2[i] + bh2[i]; }
}

// gather embedding rows -> f16 A [4096][512], row r = t*16+b
__global__ void k_embed(const int* __restrict__ tok, const float* __restrict__ emb,
                        _Float16* __restrict__ A) {
    int idx = blockIdx.x * 256 + threadIdx.x;
    if (idx >= NROW * (EMB / 4)) return;
    int r = idx >> 7, c4 = idx & 127;
    int t = r >> 4, b = r & 15;
    int token = tok[b * SS + t];
    float4 v = ((const float4*)(emb + (size_t)token * EMB))[c4];
    half4 o = {(_Float16)v.x, (_Float16)v.y, (_Float16)v.z, (_Float16)v.w};
    ((half4*)(A + (size_t)r * EMB))[c4] = o;
}

// ---------------- f16 MFMA GEMM: C[M,N] = A[M,K] @ B[N,K]^T + bias[N] ----------------
__global__ __launch_bounds__(256) void k_gemm_bt(
    const _Float16* __restrict__ A, const _Float16* __restrict__ B,
    const float* __restrict__ bias, float* __restrict__ C,
    int M, int N, int K, int scatter) {
    __shared__ __align__(16) _Float16 As[128 * 32];
    __shared__ __align__(16) _Float16 Bs[128 * 32];
    int tid = threadIdx.x;
    int wave = tid >> 6, lane = tid & 63;
    int bRow = blockIdx.y * 128, bCol = blockIdx.x * 128;
    int wr = (wave >> 1) * 64, wc = (wave & 1) * 64;
    f32x4 acc[4][4] = {};

    int lrow = lane & 15, khalf = (lane >> 4) * 8;

    for (int kt = 0; kt < K; kt += 32) {
#pragma unroll
        for (int q = 0; q < 2; ++q) {
            int chunk = tid + 256 * q;
            int row = chunk >> 2, c8 = (chunk & 3) * 8;
            half8 va = *(const half8*)(A + (size_t)(bRow + row) * K + kt + c8);
            *(half8*)(&As[row * 32 + c8]) = va;
            half8 vb = *(const half8*)(B + (size_t)(bCol + row) * K + kt + c8);
            *(half8*)(&Bs[row * 32 + c8]) = vb;
        }
        __syncthreads();
        half8 a[4], b[4];
#pragma unroll
        for (int i = 0; i < 4; ++i)
            a[i] = *(const half8*)(&As[(wr + 16 * i + lrow) * 32 + khalf]);
#pragma unroll
        for (int j = 0; j < 4; ++j)
            b[j] = *(const half8*)(&Bs[(wc + 16 * j + lrow) * 32 + khalf]);
#pragma unroll
        for (int i = 0; i < 4; ++i)
#pragma unroll
            for (int j = 0; j < 4; ++j)
                acc[i][j] = __builtin_amdgcn_mfma_f32_16x16x32_f16(a[i], b[j], acc[i][j], 0, 0, 0);
        __syncthreads();
    }

    int lcol = lane & 15, lrow4 = (lane >> 4) * 4;
#pragma unroll
    for (int i = 0; i < 4; ++i)
#pragma unroll
        for (int j = 0; j < 4; ++j)
#pragma unroll
            for (int q = 0; q < 4; ++q) {
                int gr = bRow + wr + 16 * i + lrow4 + q;
                int gc = bCol + wc + 16 * j + lcol;
                float v = acc[i][j][q] + bias[gc];
                size_t orow = scatter ? (size_t)(((gr & 15) << 8) | (gr >> 4)) : (size_t)gr;
                C[orow * (size_t)N + gc] = v;
            }
}

// ---------------- persistent LSTM layer kernel ----------------
// 64 blocks x 256 threads. Block bid owns h-cols [bid*16, bid*16+16).
// Wave w = gate w (i,f,g,o). W_hh slice pinned in VGPRs (opaque-asm keep-alive).
// Cross-block h + barrier flags go through the MALL (sc0 sc1), release via
// s_waitcnt vmcnt(0) only — no cache-maintenance fences, no RMW atomics.
// hbuf layout: [slot][b*1024 + col] f16. flags: 64 slots * 64B per layer.
__global__ __launch_bounds__(256, 1) void k_lstm(
    const float* __restrict__ X,             // [4096][4096] f32: x@Wih^T + both biases
    const _Float16* __restrict__ Whh,        // [4096][1024] f16 row-major
    _Float16* __restrict__ hbuf,             // [2][16384] f16 ping-pong
    _Float16* __restrict__ hseq,             // [4096][1024] f16 row-major out
    unsigned* __restrict__ flags) {
    __shared__ __align__(16) _Float16 hs[16][1032];  // +16B pad: ~2-way banks on frag reads
    __shared__ float gs[4][1024];
    int tid = threadIdx.x;
    int w = tid >> 6, l = tid & 63;
    int bid = blockIdx.x;

    // ---- W_hh slice pinned in VGPRs (opaque asm prevents remat/reload) ----
    half8 wf[32];
    {
        const _Float16* wp = Whh + (size_t)(w * HID + bid * 16 + (l & 15)) * HID + (l >> 4) * 8;
#pragma unroll
        for (int kt = 0; kt < 32; ++kt) {
            half8 v = *(const half8*)(wp + kt * 32);
            asm volatile("" : "+v"(v));
            wf[kt] = v;
        }
    }

    int eb = tid >> 4, ecol = tid & 15;
    int gidx = ((eb >> 2) * 16 + ecol) * 4 + (eb & 3);
    int cg = bid * 16 + ecol;
    float creg = 0.f;

    const float* xbase = X + (size_t)w * HID + bid * 16 + (l & 15);
    int bq = (l >> 4) * 4;
    f32x4 xreg;
    {   // X for t=0
        xreg[0] = xbase[0]; xreg[1] = xbase[4096];
        xreg[2] = xbase[8192]; xreg[3] = xbase[12288];
    }

    for (int t = 0; t < SS; ++t) {
        // ---- X prefetch for t+1 (plain loads; latency overlaps the h wait) ----
        int tn = (t + 1 < SS) ? t + 1 : SS - 1;
        const float* xp = xbase + (size_t)(tn * 16 + bq) * 4096;
        float xn0 = xp[0], xn1 = xp[4096], xn2 = xp[8192], xn3 = xp[12288];

        // ---- stage h(slot t&1) -> LDS via MALL-coherent loads ----
        const _Float16* hb = hbuf + (t & 1) * 16384 + tid * 8;
        half8 hv[8];
#pragma unroll
        for (int j = 0; j < 8; ++j) hv[j] = ldg_h8_cc(hb + j * 2048);
        asm volatile("s_waitcnt vmcnt(0)" ::: "memory");
        __builtin_amdgcn_sched_barrier(0);
#pragma unroll
        for (int j = 0; j < 8; ++j) {
            int chunk = tid + j * 256;
            *(half8*)(&hs[chunk >> 7][(chunk & 127) * 8]) = hv[j];
        }
        __syncthreads();

        // ---- fragments + 32 MFMAs in 4 independent K-chains ----
        half8 ha[32];
#pragma unroll
        for (int kt = 0; kt < 32; ++kt)
            ha[kt] = *(const half8*)(&hs[l & 15][kt * 32 + (l >> 4) * 8]);
        f32x4 a0 = xreg, a1 = {}, a2 = {}, a3 = {};
#pragma unroll
        for (int i = 0; i < 8; ++i) {
            a0 = __builtin_amdgcn_mfma_f32_16x16x32_f16(ha[i],      wf[i],      a0, 0, 0, 0);
            a1 = __builtin_amdgcn_mfma_f32_16x16x32_f16(ha[8 + i],  wf[8 + i],  a1, 0, 0, 0);
            a2 = __builtin_amdgcn_mfma_f32_16x16x32_f16(ha[16 + i], wf[16 + i], a2, 0, 0, 0);
            a3 = __builtin_amdgcn_mfma_f32_16x16x32_f16(ha[24 + i], wf[24 + i], a3, 0, 0, 0);
        }
        a0 = (a0 + a1) + (a2 + a3);

        // ---- gate exchange via LDS ----
        *(f32x4*)(&gs[w][l * 4]) = a0;
        __syncthreads();

        // ---- elementwise LSTM cell: thread owns (b=eb, col=cg) ----
        float gi = gs[0][gidx], gf = gs[1][gidx], gg = gs[2][gidx], go = gs[3][gidx];
        float cn = sigf(gf) * creg + sigf(gi) * tanh_c(gg);
        float hn = sigf(go) * tanh_c(cn);
        creg = cn;
        _Float16 hh = (_Float16)hn;
        unsigned short hu;
        __builtin_memcpy(&hu, &hh, 2);
        hseq[(size_t)(t * 16 + eb) * HID + cg] = hh;
        stg_u16_cc(hbuf + ((t + 1) & 1) * 16384 + (size_t)eb * 1024 + cg, hu);
        xreg[0] = xn0; xreg[1] = xn1; xreg[2] = xn2; xreg[3] = xn3;

        // ---- grid barrier: release own flag, poll all 64 in parallel ----
        if (t < SS - 1) {
            asm volatile("s_waitcnt vmcnt(0)" ::: "memory");  // h stores acked at MALL
            __syncthreads();
            if (tid == 0) stg_u32_cc(flags + (size_t)bid * 16, (unsigned)(t + 1));
            if (tid < RBLK) {
                const unsigned* fp = flags + (size_t)tid * 16;
                while (ldg_u32_cc(fp) <= (unsigned)t) __builtin_amdgcn_s_sleep(1);
            }
            __syncthreads();
        }
    }
}

// ---------------- log-softmax ----------------
__global__ __launch_bounds__(256) void k_lse(const float* __restrict__ logits,
                                             float* __restrict__ lse) {
    int r = blockIdx.x;
    const float* row = logits + (size_t)r * VOC;
    int tid = threadIdx.x;
    float m = -3.4e38f, s = 0.f;
    for (int i = 0; i < VOC / 256; ++i) {
        float x = row[tid + 256 * i];
        float mn = fmaxf(m, x);
        s = s * __expf(m - mn) + __expf(x - mn);
        m = mn;
    }
#pragma unroll
    for (int off = 1; off < 64; off <<= 1) {
        float m2 = __shfl_xor(m, off);
        float s2 = __shfl_xor(s, off);
        float mn = fmaxf(m, m2);
        s = s * __expf(m - mn) + s2 * __expf(m2 - mn);
        m = mn;
    }
    __shared__ float sm[4], ss_[4];
    int wv = tid >> 6;
    if ((tid & 63) == 0) { sm[wv] = m; ss_[wv] = s; }
    __syncthreads();
    if (tid == 0) {
        m = sm[0]; s = ss_[0];
        for (int i = 1; i < 4; ++i) {
            float mn = fmaxf(m, sm[i]);
            s = s * __expf(m - mn) + ss_[i] * __expf(sm[i] - mn);
            m = mn;
        }
        lse[r] = m + __logf(s);
    }
}

__global__ void k_sub(float* __restrict__ logits, const float* __restrict__ lse) {
    int r = blockIdx.y;
    int i4 = blockIdx.x * 256 + threadIdx.x;
    if (i4 >= VOC / 4) return;
    float l = lse[r];
    float4* p = (float4*)(logits + (size_t)r * VOC) + i4;
    float4 v = *p;
    v.x -= l; v.y -= l; v.z -= l; v.w -= l;
    *p = v;
}

// ---------------- launch ----------------
extern "C" void kernel_launch(void* const* d_in, const int* in_sizes, int n_in,
                              void* d_out, int out_size, void* d_ws, size_t ws_size,
                              hipStream_t stream) {
    const int*   tok   = (const int*)d_in[0];
    const float* emb   = (const float*)d_in[1];
    const float* W_ih1 = (const float*)d_in[2];
    const float* W_hh1 = (const float*)d_in[3];
    const float* b_ih1 = (const float*)d_in[4];
    const float* b_hh1 = (const float*)d_in[5];
    const float* W_ih2 = (const float*)d_in[6];
    const float* W_hh2 = (const float*)d_in[7];
    const float* b_ih2 = (const float*)d_in[8];
    const float* b_hh2 = (const float*)d_in[9];
    const float* W_log = (const float*)d_in[10];
    const float* b_log = (const float*)d_in[11];
    float* out = (float*)d_out;

    char* w = (char*)d_ws;
    auto alloc = [&](size_t bytes) {
        char* p = w;
        w += (bytes + 255) & ~(size_t)255;
        return p;
    };
    _Float16* Wih1h = (_Float16*)alloc((size_t)4096 * 512 * 2);
    _Float16* Whh1h = (_Float16*)alloc((size_t)4096 * 1024 * 2);
    _Float16* Wih2h = (_Float16*)alloc((size_t)4096 * 1024 * 2);
    _Float16* Whh2h = (_Float16*)alloc((size_t)4096 * 1024 * 2);
    _Float16* Wlogh = (_Float16*)alloc((size_t)VOC * 1024 * 2);
    _Float16* Abuf  = (_Float16*)alloc((size_t)4096 * 512 * 2);
    float* X        = (float*)alloc((size_t)4096 * 4096 * 4);
    _Float16* h1seq = (_Float16*)alloc((size_t)4096 * 1024 * 2);
    _Float16* h2seq = (_Float16*)alloc((size_t)4096 * 1024 * 2);
    float* b1s      = (float*)alloc(4096 * 4);
    float* b2s      = (float*)alloc(4096 * 4);
    _Float16* hbuf  = (_Float16*)alloc((size_t)2 * 16384 * 2);  // 64 KB ping-pong
    unsigned* flags = (unsigned*)alloc(2 * RBLK * 64);          // 2 layers * 64 slots * 64B
    float* lse      = (float*)alloc(4096 * 4);

    // zero h ping-pong + both flag arrays (every launch: graph-replay safe)
    k_zero<<<72, 256, 0, stream>>>((float*)hbuf, 16384 + 2 * RBLK * 16);

    // weight conversions f32 -> f16 (idempotent)
    k_f32_to_f16<<<2048, 256, 0, stream>>>(W_ih1, Wih1h, 4096 * 512 / 4);
    k_f32_to_f16<<<2048, 256, 0, stream>>>(W_hh1, Whh1h, 4096 * 1024 / 4);
    k_f32_to_f16<<<2048, 256, 0, stream>>>(W_ih2, Wih2h, 4096 * 1024 / 4);
    k_f32_to_f16<<<2048, 256, 0, stream>>>(W_hh2, Whh2h, 4096 * 1024 / 4);
    k_f32_to_f16<<<2048, 256, 0, stream>>>(W_log, Wlogh, VOC * 1024 / 4);
    k_bias<<<16, 256, 0, stream>>>(b_ih1, b_hh1, b_ih2, b_hh2, b1s, b2s);

    // X1 = embed @ W_ih1^T + (b_ih1 + b_hh1)
    k_embed<<<2048, 256, 0, stream>>>(tok, emb, Abuf);
    k_gemm_bt<<<dim3(32, 32), 256, 0, stream>>>(Abuf, Wih1h, b1s, X, 4096, 4096, 512, 0);

    // layer 1 recurrence (persistent, 64 blocks)
    k_lstm<<<RBLK, 256, 0, stream>>>(X, Whh1h, hbuf, h1seq, flags);

    // re-zero h ping-pong slot 0 for layer 2
    k_zero<<<32, 256, 0, stream>>>((float*)hbuf, 8192);

    // X2 = h1_seq @ W_ih2^T + (b_ih2 + b_hh2)
    k_gemm_bt<<<dim3(32, 32), 256, 0, stream>>>(h1seq, Wih2h, b2s, X, 4096, 4096, 1024, 0);

    // layer 2 recurrence
    k_lstm<<<RBLK, 256, 0, stream>>>(X, Whh2h, hbuf, h2seq, flags + RBLK * 16);

    // logits = h2_seq @ W_log^T + b_log, scattered to [b][t][v]
    k_gemm_bt<<<dim3(VOC / 128, 32), 256, 0, stream>>>(h2seq, Wlogh, b_log, out,
                                                       4096, VOC, 1024, 1);

    // log-softmax in place
    k_lse<<<4096, 256, 0, stream>>>(out, lse);
    k_sub<<<dim3(32, 4096), 256, 0, stream>>>(out, lse);
}

// Round 4
// 2410.953 us; speedup vs baseline: 2.8353x; 1.0356x over previous
//
#include <hip/hip_runtime.h>
#include <hip/hip_bf16.h>

typedef __attribute__((ext_vector_type(8))) _Float16 half8;
typedef __attribute__((ext_vector_type(4))) _Float16 half4;
typedef __attribute__((ext_vector_type(4))) float f32x4;

#define VOC 32000
#define EMB 512
#define HID 1024
#define SS  256
#define NROW 4096   // S*B rows, ordered r = t*16 + b
#define RBLK 64     // persistent recurrence blocks

__device__ __forceinline__ float sigf(float x) {
    return 1.f / (1.f + __expf(-x));
}
__device__ __forceinline__ float tanh_c(float x) {
    x = fminf(fmaxf(x, -15.f), 15.f);
    float e = __expf(2.f * x);
    return (e - 1.f) / (e + 1.f);
}

// ---- MALL-coherent (bypass L1+L2) primitives for cross-block traffic ----
__device__ __forceinline__ half8 ldg_h8_cc(const _Float16* p) {
    half8 r;
    asm volatile("global_load_dwordx4 %0, %1, off sc0 sc1" : "=v"(r) : "v"(p));
    return r;
}
__device__ __forceinline__ void stg_h8_cc(_Float16* p, half8 v) {
    asm volatile("global_store_dwordx4 %0, %1, off sc0 sc1" :: "v"(p), "v"(v) : "memory");
}
__device__ __forceinline__ void stg_u32_cc(unsigned* p, unsigned v) {
    asm volatile("global_store_dword %0, %1, off sc0 sc1" :: "v"(p), "v"(v) : "memory");
}
__device__ __forceinline__ unsigned ldg_u32_cc(const unsigned* p) {
    unsigned v;
    asm volatile("global_load_dword %0, %1, off sc0 sc1\n\ts_waitcnt vmcnt(0)"
                 : "=v"(v) : "v"(p) : "memory");
    return v;
}

// async global->LDS, 16B per lane; lds base must be wave-uniform
__device__ __forceinline__ void gload16(const void* g, void* lds) {
    __builtin_amdgcn_global_load_lds(
        (const __attribute__((address_space(1))) unsigned int*)(uintptr_t)g,
        (__attribute__((address_space(3))) unsigned int*)(unsigned int)(uintptr_t)lds,
        16, 0, 0);
}

// ---------------- utility kernels ----------------
__global__ void k_zero(float* p, int n) {
    int i = blockIdx.x * blockDim.x + threadIdx.x;
    int st = gridDim.x * blockDim.x;
    for (; i < n; i += st) p[i] = 0.f;
}

__global__ void k_f32_to_f16(const float* __restrict__ src,
                             _Float16* __restrict__ dst, int n4) {
    int i = blockIdx.x * blockDim.x + threadIdx.x;
    int st = gridDim.x * blockDim.x;
    for (; i < n4; i += st) {
        float4 v = ((const float4*)src)[i];
        half4 o = {(_Float16)v.x, (_Float16)v.y, (_Float16)v.z, (_Float16)v.w};
        ((half4*)dst)[i] = o;
    }
}

__global__ void k_bias(const float* bi1, const float* bh1,
                       const float* bi2, const float* bh2,
                       float* b1, float* b2) {
    int i = blockIdx.x * blockDim.x + threadIdx.x;
    if (i < 4 * HID) { b1[i] = bi1[i] + bh1[i]; b2[i] = bi2[i] + bh2[i]; }
}

// gather embedding rows -> f16 A [4096][512], row r = t*16+b
__global__ void k_embed(const int* __restrict__ tok, const float* __restrict__ emb,
                        _Float16* __restrict__ A) {
    int idx = blockIdx.x * 256 + threadIdx.x;
    if (idx >= NROW * (EMB / 4)) return;
    int r = idx >> 7, c4 = idx & 127;
    int t = r >> 4, b = r & 15;
    int token = tok[b * SS + t];
    float4 v = ((const float4*)(emb + (size_t)token * EMB))[c4];
    half4 o = {(_Float16)v.x, (_Float16)v.y, (_Float16)v.z, (_Float16)v.w};
    ((half4*)(A + (size_t)r * EMB))[c4] = o;
}

// ---------------- f16 MFMA GEMM: C[M,N] = A[M,K] @ B[N,K]^T + bias[N] ----------------
// 128x128 tile, BK=32, global_load_lds(16B) staging (m97 pattern).
__global__ __launch_bounds__(256) void k_gemm_bt(
    const _Float16* __restrict__ A, const _Float16* __restrict__ B,
    const float* __restrict__ bias, float* __restrict__ C,
    int M, int N, int K, int scatter) {
    __shared__ __align__(16) _Float16 As[128 * 32];
    __shared__ __align__(16) _Float16 Bs[128 * 32];
    int tid = threadIdx.x;
    int wave = tid >> 6, lane = tid & 63;
    int bRow = blockIdx.y * 128, bCol = blockIdx.x * 128;
    int wr = (wave >> 1) * 64, wc = (wave & 1) * 64;
    f32x4 acc[4][4] = {};

    int lrow = lane & 15, khalf = (lane >> 4) * 8;

    for (int kt = 0; kt < K; kt += 32) {
#pragma unroll
        for (int q = 0; q < 2; ++q) {
            int ci = q * 256 + wave * 64 + lane;        // 16B chunk id, 0..511
            int row = ci >> 2, c8 = (ci & 3) * 8;
            int ldsoff = (q * 256 + wave * 64) * 16;    // wave-uniform byte base
            gload16(A + (size_t)(bRow + row) * K + kt + c8, (char*)As + ldsoff);
            gload16(B + (size_t)(bCol + row) * K + kt + c8, (char*)Bs + ldsoff);
        }
        __syncthreads();
        half8 a[4], b[4];
#pragma unroll
        for (int i = 0; i < 4; ++i)
            a[i] = *(const half8*)(&As[(wr + 16 * i + lrow) * 32 + khalf]);
#pragma unroll
        for (int j = 0; j < 4; ++j)
            b[j] = *(const half8*)(&Bs[(wc + 16 * j + lrow) * 32 + khalf]);
#pragma unroll
        for (int i = 0; i < 4; ++i)
#pragma unroll
            for (int j = 0; j < 4; ++j)
                acc[i][j] = __builtin_amdgcn_mfma_f32_16x16x32_f16(a[i], b[j], acc[i][j], 0, 0, 0);
        __syncthreads();
    }

    int lcol = lane & 15, lrow4 = (lane >> 4) * 4;
#pragma unroll
    for (int i = 0; i < 4; ++i)
#pragma unroll
        for (int j = 0; j < 4; ++j)
#pragma unroll
            for (int q = 0; q < 4; ++q) {
                int gr = bRow + wr + 16 * i + lrow4 + q;
                int gc = bCol + wc + 16 * j + lcol;
                float v = acc[i][j][q] + bias[gc];
                size_t orow = scatter ? (size_t)(((gr & 15) << 8) | (gr >> 4)) : (size_t)gr;
                C[orow * (size_t)N + gc] = v;
            }
}

// ---------------- persistent LSTM layer kernel ----------------
// 64 blocks x 256 threads. Block bid owns h-cols [bid*16, bid*16+16).
// Wave w = gate w (i,f,g,o). W_hh slice pinned in VGPRs (peak pressure kept
// <256 via chunked ha). hbuf layout: [slot][bid*256 + b*16 + c] f16;
// cross-block h + flags via MALL (sc0 sc1); release = vmcnt(0) only.
__global__ __launch_bounds__(256, 1) void k_lstm(
    const float* __restrict__ X,             // [4096][4096] f32: x@Wih^T + both biases
    const _Float16* __restrict__ Whh,        // [4096][1024] f16 row-major
    _Float16* __restrict__ hbuf,             // [2][16384] f16 ping-pong (block-sliced)
    _Float16* __restrict__ hseq,             // [4096][1024] f16 row-major out
    unsigned* __restrict__ flags) {
    __shared__ __align__(16) _Float16 hs[16][1032];  // row=batch, col=global h col
    __shared__ float gs[4][1024];
    __shared__ __align__(16) _Float16 hstage[256];   // block's h slice [b][c16]
    int tid = threadIdx.x;
    int w = tid >> 6, l = tid & 63;
    int bid = blockIdx.x;

    // ---- W_hh slice pinned in VGPRs (opaque asm: cannot be rematerialized) ----
    half8 wf[32];
    {
        const _Float16* wp = Whh + (size_t)(w * HID + bid * 16 + (l & 15)) * HID + (l >> 4) * 8;
#pragma unroll
        for (int kt = 0; kt < 32; ++kt) {
            half8 v = *(const half8*)(wp + kt * 32);
            asm volatile("" : "+v"(v));
            wf[kt] = v;
        }
    }

    int eb = tid >> 4, ecol = tid & 15;
    int gidx = ((eb >> 2) * 16 + ecol) * 4 + (eb & 3);
    int cg = bid * 16 + ecol;
    float creg = 0.f;

    const float* xbase = X + (size_t)w * HID + bid * 16 + (l & 15);
    int bq = (l >> 4) * 4;
    f32x4 xreg;
    {   // X for t=0 (rows bq..bq+3)
        const float* xp = xbase + (size_t)bq * 4096;
        xreg[0] = xp[0]; xreg[1] = xp[4096];
        xreg[2] = xp[8192]; xreg[3] = xp[12288];
    }

    for (int t = 0; t < SS; ++t) {
        // ---- X prefetch for t+1 (latency hides under the h wait) ----
        int tn = (t + 1 < SS) ? t + 1 : SS - 1;
        const float* xp = xbase + (size_t)(tn * 16 + bq) * 4096;
        float xn0 = xp[0], xn1 = xp[4096], xn2 = xp[8192], xn3 = xp[12288];

        // ---- stage h(slot t&1) -> LDS via MALL-coherent loads ----
        // chunk ci = tid + j*256 covers hbuf halves [ci*8, ci*8+8):
        //   bid' = ci>>5, b = (ci>>1)&15, c8 = (ci&1)*8
        {
            const _Float16* hb = hbuf + (t & 1) * 16384 + tid * 8;
            half8 hv[8];
#pragma unroll
            for (int j = 0; j < 8; ++j) hv[j] = ldg_h8_cc(hb + j * 2048);
            asm volatile("s_waitcnt vmcnt(0)" ::: "memory");
            __builtin_amdgcn_sched_barrier(0);
#pragma unroll
            for (int j = 0; j < 8; ++j) {
                int ci = tid + j * 256;
                int b = (ci >> 1) & 15;
                int col = ((ci >> 5) << 4) + (ci & 1) * 8;
                *(half8*)(&hs[b][col]) = hv[j];
            }
        }
        __syncthreads();

        // ---- 32 MFMAs in 4 chunks of 8 (keeps live ha small) ----
        f32x4 a0 = xreg, a1 = {}, a2 = {}, a3 = {};
#pragma unroll
        for (int c = 0; c < 4; ++c) {
            half8 ha[8];
#pragma unroll
            for (int j = 0; j < 8; ++j)
                ha[j] = *(const half8*)(&hs[l & 15][(c * 8 + j) * 32 + (l >> 4) * 8]);
            a0 = __builtin_amdgcn_mfma_f32_16x16x32_f16(ha[0], wf[c * 8 + 0], a0, 0, 0, 0);
            a1 = __builtin_amdgcn_mfma_f32_16x16x32_f16(ha[1], wf[c * 8 + 1], a1, 0, 0, 0);
            a2 = __builtin_amdgcn_mfma_f32_16x16x32_f16(ha[2], wf[c * 8 + 2], a2, 0, 0, 0);
            a3 = __builtin_amdgcn_mfma_f32_16x16x32_f16(ha[3], wf[c * 8 + 3], a3, 0, 0, 0);
            a0 = __builtin_amdgcn_mfma_f32_16x16x32_f16(ha[4], wf[c * 8 + 4], a0, 0, 0, 0);
            a1 = __builtin_amdgcn_mfma_f32_16x16x32_f16(ha[5], wf[c * 8 + 5], a1, 0, 0, 0);
            a2 = __builtin_amdgcn_mfma_f32_16x16x32_f16(ha[6], wf[c * 8 + 6], a2, 0, 0, 0);
            a3 = __builtin_amdgcn_mfma_f32_16x16x32_f16(ha[7], wf[c * 8 + 7], a3, 0, 0, 0);
        }
        a0 = (a0 + a1) + (a2 + a3);

        // ---- gate exchange via LDS ----
        *(f32x4*)(&gs[w][l * 4]) = a0;
        __syncthreads();

        // ---- elementwise LSTM cell: thread owns (b=eb, col=cg) ----
        float gi = gs[0][gidx], gf = gs[1][gidx], gg = gs[2][gidx], go = gs[3][gidx];
        float cn = sigf(gf) * creg + sigf(gi) * tanh_c(gg);
        float hn = sigf(go) * tanh_c(cn);
        creg = cn;
        hstage[eb * 16 + ecol] = (_Float16)hn;
        xreg[0] = xn0; xreg[1] = xn1; xreg[2] = xn2; xreg[3] = xn3;
        __syncthreads();   // hstage ready; all gs/hs reads complete

        // ---- vectorized slice stores: wave0 -> hbuf (MALL), wave1 -> hseq ----
        if (w == 1 && l < 32) {
            int b = l >> 1, c8 = (l & 1) * 8;
            *(half8*)(hseq + (size_t)(t * 16 + b) * HID + bid * 16 + c8) =
                *(const half8*)(&hstage[l * 8]);
        }
        if (t < SS - 1) {
            if (w == 0 && l < 32)
                stg_h8_cc(hbuf + ((t + 1) & 1) * 16384 + bid * 256 + l * 8,
                          *(const half8*)(&hstage[l * 8]));
            // ---- grid barrier: release own flag, poll all 64 in parallel ----
            asm volatile("s_waitcnt vmcnt(0)" ::: "memory");  // h stores acked at MALL
            __syncthreads();
            if (tid == 0) stg_u32_cc(flags + (size_t)bid * 16, (unsigned)(t + 1));
            if (tid < RBLK) {
                const unsigned* fp = flags + (size_t)tid * 16;
                while (ldg_u32_cc(fp) <= (unsigned)t) __builtin_amdgcn_s_sleep(1);
            }
            __syncthreads();
        }
    }
}

// ---------------- fused log-softmax (row register-resident) ----------------
__global__ __launch_bounds__(320) void k_lsm(float* __restrict__ logits) {
    int r = blockIdx.x, tid = threadIdx.x;
    float* row = logits + (size_t)r * VOC;
    f32x4 v[25];
    float m = -3.4e38f;
#pragma unroll
    for (int j = 0; j < 25; ++j) {
        v[j] = ((const f32x4*)row)[tid + 320 * j];
        m = fmaxf(fmaxf(fmaxf(m, v[j][0]), fmaxf(v[j][1], v[j][2])), v[j][3]);
    }
#pragma unroll
    for (int off = 1; off < 64; off <<= 1) m = fmaxf(m, __shfl_xor(m, off));
    __shared__ float sm[5], ssum[5];
    int wv = tid >> 6;
    if ((tid & 63) == 0) sm[wv] = m;
    __syncthreads();
    m = fmaxf(fmaxf(fmaxf(sm[0], sm[1]), fmaxf(sm[2], sm[3])), sm[4]);
    float s = 0.f;
#pragma unroll
    for (int j = 0; j < 25; ++j)
        s += (__expf(v[j][0] - m) + __expf(v[j][1] - m)) +
             (__expf(v[j][2] - m) + __expf(v[j][3] - m));
#pragma unroll
    for (int off = 1; off < 64; off <<= 1) s += __shfl_xor(s, off);
    if ((tid & 63) == 0) ssum[wv] = s;
    __syncthreads();
    s = (ssum[0] + ssum[1]) + (ssum[2] + ssum[3]) + ssum[4];
    float lse = m + __logf(s);
#pragma unroll
    for (int j = 0; j < 25; ++j) {
        f32x4 o = v[j];
        o[0] -= lse; o[1] -= lse; o[2] -= lse; o[3] -= lse;
        ((f32x4*)row)[tid + 320 * j] = o;
    }
}

// ---------------- launch ----------------
extern "C" void kernel_launch(void* const* d_in, const int* in_sizes, int n_in,
                              void* d_out, int out_size, void* d_ws, size_t ws_size,
                              hipStream_t stream) {
    const int*   tok   = (const int*)d_in[0];
    const float* emb   = (const float*)d_in[1];
    const float* W_ih1 = (const float*)d_in[2];
    const float* W_hh1 = (const float*)d_in[3];
    const float* b_ih1 = (const float*)d_in[4];
    const float* b_hh1 = (const float*)d_in[5];
    const float* W_ih2 = (const float*)d_in[6];
    const float* W_hh2 = (const float*)d_in[7];
    const float* b_ih2 = (const float*)d_in[8];
    const float* b_hh2 = (const float*)d_in[9];
    const float* W_log = (const float*)d_in[10];
    const float* b_log = (const float*)d_in[11];
    float* out = (float*)d_out;

    char* w = (char*)d_ws;
    auto alloc = [&](size_t bytes) {
        char* p = w;
        w += (bytes + 255) & ~(size_t)255;
        return p;
    };
    _Float16* Wih1h = (_Float16*)alloc((size_t)4096 * 512 * 2);
    _Float16* Whh1h = (_Float16*)alloc((size_t)4096 * 1024 * 2);
    _Float16* Wih2h = (_Float16*)alloc((size_t)4096 * 1024 * 2);
    _Float16* Whh2h = (_Float16*)alloc((size_t)4096 * 1024 * 2);
    _Float16* Wlogh = (_Float16*)alloc((size_t)VOC * 1024 * 2);
    _Float16* Abuf  = (_Float16*)alloc((size_t)4096 * 512 * 2);
    float* X        = (float*)alloc((size_t)4096 * 4096 * 4);
    _Float16* h1seq = (_Float16*)alloc((size_t)4096 * 1024 * 2);
    _Float16* h2seq = (_Float16*)alloc((size_t)4096 * 1024 * 2);
    float* b1s      = (float*)alloc(4096 * 4);
    float* b2s      = (float*)alloc(4096 * 4);
    _Float16* hbuf  = (_Float16*)alloc((size_t)2 * 16384 * 2);  // 64 KB ping-pong
    unsigned* flags = (unsigned*)alloc(2 * RBLK * 64);          // 2 layers * 64 slots * 64B
    float* lse      = (float*)alloc(4096 * 4);
    (void)lse;

    // zero h ping-pong + both flag arrays (every launch: graph-replay safe)
    k_zero<<<72, 256, 0, stream>>>((float*)hbuf, 16384 + 2 * RBLK * 16);

    // weight conversions f32 -> f16 (idempotent)
    k_f32_to_f16<<<2048, 256, 0, stream>>>(W_ih1, Wih1h, 4096 * 512 / 4);
    k_f32_to_f16<<<2048, 256, 0, stream>>>(W_hh1, Whh1h, 4096 * 1024 / 4);
    k_f32_to_f16<<<2048, 256, 0, stream>>>(W_ih2, Wih2h, 4096 * 1024 / 4);
    k_f32_to_f16<<<2048, 256, 0, stream>>>(W_hh2, Whh2h, 4096 * 1024 / 4);
    k_f32_to_f16<<<2048, 256, 0, stream>>>(W_log, Wlogh, VOC * 1024 / 4);
    k_bias<<<16, 256, 0, stream>>>(b_ih1, b_hh1, b_ih2, b_hh2, b1s, b2s);

    // X1 = embed @ W_ih1^T + (b_ih1 + b_hh1)
    k_embed<<<2048, 256, 0, stream>>>(tok, emb, Abuf);
    k_gemm_bt<<<dim3(32, 32), 256, 0, stream>>>(Abuf, Wih1h, b1s, X, 4096, 4096, 512, 0);

    // layer 1 recurrence (persistent, 64 blocks)
    k_lstm<<<RBLK, 256, 0, stream>>>(X, Whh1h, hbuf, h1seq, flags);

    // re-zero h ping-pong slot 0 for layer 2
    k_zero<<<32, 256, 0, stream>>>((float*)hbuf, 8192);

    // X2 = h1_seq @ W_ih2^T + (b_ih2 + b_hh2)
    k_gemm_bt<<<dim3(32, 32), 256, 0, stream>>>(h1seq, Wih2h, b2s, X, 4096, 4096, 1024, 0);

    // layer 2 recurrence
    k_lstm<<<RBLK, 256, 0, stream>>>(X, Whh2h, hbuf, h2seq, flags + RBLK * 16);

    // logits = h2_seq @ W_log^T + b_log, scattered to [b][t][v]
    k_gemm_bt<<<dim3(VOC / 128, 32), 256, 0, stream>>>(h2seq, Wlogh, b_log, out,
                                                       4096, VOC, 1024, 1);

    // fused log-softmax in place
    k_lsm<<<4096, 320, 0, stream>>>(out);
}

// Round 5
// 1877.579 us; speedup vs baseline: 3.6408x; 1.2841x over previous
//
#include <hip/hip_runtime.h>
#include <hip/hip_bf16.h>

typedef __attribute__((ext_vector_type(8))) _Float16 half8;
typedef __attribute__((ext_vector_type(4))) _Float16 half4;
typedef __attribute__((ext_vector_type(4))) float f32x4;

#define VOC 32000
#define EMB 512
#define HID 1024
#define SS  256
#define NROW 4096   // S*B rows, ordered r = t*16 + b
#define RBLK 128    // persistent blocks: 64 layer-1 + 64 layer-2

__device__ __forceinline__ float sigf(float x) {
    return 1.f / (1.f + __expf(-x));
}
__device__ __forceinline__ float tanh_c(float x) {
    x = fminf(fmaxf(x, -15.f), 15.f);
    float e = __expf(2.f * x);
    return (e - 1.f) / (e + 1.f);
}

// ---- MALL-coherent (bypass L1+L2) primitives for cross-block traffic ----
__device__ __forceinline__ half8 ldg_h8_cc(const _Float16* p) {
    half8 r;
    asm volatile("global_load_dwordx4 %0, %1, off sc0 sc1" : "=v"(r) : "v"(p));
    return r;
}
__device__ __forceinline__ void stg_h8_cc(_Float16* p, half8 v) {
    asm volatile("global_store_dwordx4 %0, %1, off sc0 sc1" :: "v"(p), "v"(v) : "memory");
}
__device__ __forceinline__ void stg_u32_cc(unsigned* p, unsigned v) {
    asm volatile("global_store_dword %0, %1, off sc0 sc1" :: "v"(p), "v"(v) : "memory");
}
__device__ __forceinline__ unsigned ldg_u32_cc(const unsigned* p) {
    unsigned v;
    asm volatile("global_load_dword %0, %1, off sc0 sc1\n\ts_waitcnt vmcnt(0)"
                 : "=v"(v) : "v"(p) : "memory");
    return v;
}
// force a weight fragment into the AGPR file (half8 = AReg_128)
__device__ __forceinline__ half8 to_agpr(half8 v) {
    asm volatile("" : "+a"(v));
    return v;
}

// async global->LDS, 16B per lane; lds base must be wave-uniform
__device__ __forceinline__ void gload16(const void* g, void* lds) {
    __builtin_amdgcn_global_load_lds(
        (const __attribute__((address_space(1))) unsigned int*)(uintptr_t)g,
        (__attribute__((address_space(3))) unsigned int*)(unsigned int)(uintptr_t)lds,
        16, 0, 0);
}

// ---------------- utility kernels ----------------
__global__ void k_zero(float* p, int n) {
    int i = blockIdx.x * blockDim.x + threadIdx.x;
    int st = gridDim.x * blockDim.x;
    for (; i < n; i += st) p[i] = 0.f;
}

__global__ void k_f32_to_f16(const float* __restrict__ src,
                             _Float16* __restrict__ dst, int n4) {
    int i = blockIdx.x * blockDim.x + threadIdx.x;
    int st = gridDim.x * blockDim.x;
    for (; i < n4; i += st) {
        float4 v = ((const float4*)src)[i];
        half4 o = {(_Float16)v.x, (_Float16)v.y, (_Float16)v.z, (_Float16)v.w};
        ((half4*)dst)[i] = o;
    }
}

__global__ void k_bias(const float* bi1, const float* bh1,
                       const float* bi2, const float* bh2,
                       float* b1, float* b2) {
    int i = blockIdx.x * blockDim.x + threadIdx.x;
    if (i < 4 * HID) { b1[i] = bi1[i] + bh1[i]; b2[i] = bi2[i] + bh2[i]; }
}

// gather embedding rows -> f16 A [4096][512], row r = t*16+b
__global__ void k_embed(const int* __restrict__ tok, const float* __restrict__ emb,
                        _Float16* __restrict__ A) {
    int idx = blockIdx.x * 256 + threadIdx.x;
    if (idx >= NROW * (EMB / 4)) return;
    int r = idx >> 7, c4 = idx & 127;
    int t = r >> 4, b = r & 15;
    int token = tok[b * SS + t];
    float4 v = ((const float4*)(emb + (size_t)token * EMB))[c4];
    half4 o = {(_Float16)v.x, (_Float16)v.y, (_Float16)v.z, (_Float16)v.w};
    ((half4*)(A + (size_t)r * EMB))[c4] = o;
}

// ---------------- f16 MFMA GEMM: C[M,N] = A[M,K] @ B[N,K]^T + bias[N] ----------------
__global__ __launch_bounds__(256) void k_gemm_bt(
    const _Float16* __restrict__ A, const _Float16* __restrict__ B,
    const float* __restrict__ bias, float* __restrict__ C,
    int M, int N, int K, int scatter) {
    __shared__ __align__(16) _Float16 As[128 * 32];
    __shared__ __align__(16) _Float16 Bs[128 * 32];
    int tid = threadIdx.x;
    int wave = tid >> 6, lane = tid & 63;
    int bRow = blockIdx.y * 128, bCol = blockIdx.x * 128;
    int wr = (wave >> 1) * 64, wc = (wave & 1) * 64;
    f32x4 acc[4][4] = {};

    int lrow = lane & 15, khalf = (lane >> 4) * 8;

    for (int kt = 0; kt < K; kt += 32) {
#pragma unroll
        for (int q = 0; q < 2; ++q) {
            int ci = q * 256 + wave * 64 + lane;
            int row = ci >> 2, c8 = (ci & 3) * 8;
            int ldsoff = (q * 256 + wave * 64) * 16;
            gload16(A + (size_t)(bRow + row) * K + kt + c8, (char*)As + ldsoff);
            gload16(B + (size_t)(bCol + row) * K + kt + c8, (char*)Bs + ldsoff);
        }
        __syncthreads();
        half8 a[4], b[4];
#pragma unroll
        for (int i = 0; i < 4; ++i)
            a[i] = *(const half8*)(&As[(wr + 16 * i + lrow) * 32 + khalf]);
#pragma unroll
        for (int j = 0; j < 4; ++j)
            b[j] = *(const half8*)(&Bs[(wc + 16 * j + lrow) * 32 + khalf]);
#pragma unroll
        for (int i = 0; i < 4; ++i)
#pragma unroll
            for (int j = 0; j < 4; ++j)
                acc[i][j] = __builtin_amdgcn_mfma_f32_16x16x32_f16(a[i], b[j], acc[i][j], 0, 0, 0);
        __syncthreads();
    }

    int lcol = lane & 15, lrow4 = (lane >> 4) * 4;
#pragma unroll
    for (int i = 0; i < 4; ++i)
#pragma unroll
        for (int j = 0; j < 4; ++j)
#pragma unroll
            for (int q = 0; q < 4; ++q) {
                int gr = bRow + wr + 16 * i + lrow4 + q;
                int gc = bCol + wc + 16 * j + lcol;
                float v = acc[i][j][q] + bias[gc];
                size_t orow = scatter ? (size_t)(((gr & 15) << 8) | (gr >> 4)) : (size_t)gr;
                C[orow * (size_t)N + gc] = v;
            }
}

// ---------------- pipelined 2-layer persistent LSTM ----------------
// 128 blocks x 256 threads. layer = bid>>6, sb = bid&63. Block owns h-cols
// [sb*16, sb*16+16). Wave w = gate w. Layer 1 (bid<64): step t=g, input X1
// (precomputed), weights Whh1 in AGPRs (128). Layer 2: step t'=g-1, input
// projection computed on the fly from h1(t') (Wih2 in AGPRs) + recurrent
// Whh2 (AGPRs) -> 256 AGPRs. Unified flag barrier per global step.
// Slot convention: h(t) lives in slot (t+1)&1; slot 0 zeroed (h(-1)=0).
__global__ __launch_bounds__(256, 1) void k_rnn(
    const float* __restrict__ X,             // [4096][4096] f32: x1@Wih1^T + b1
    const _Float16* __restrict__ Whh1,       // [4096][1024] f16
    const _Float16* __restrict__ Wih2,       // [4096][1024] f16
    const _Float16* __restrict__ Whh2,       // [4096][1024] f16
    const float* __restrict__ b2s,           // [4096] = b_ih2 + b_hh2
    _Float16* __restrict__ h1buf,            // [2][16384] f16 ping-pong
    _Float16* __restrict__ h2buf,            // [2][16384] f16 ping-pong
    _Float16* __restrict__ h2seq,            // [4096][1024] f16 out
    unsigned* __restrict__ flags) {          // 128 slots * 64B
    __shared__ __align__(16) _Float16 hsA[16][1032]; // L1: h1(t-1) | L2: h1(t')
    __shared__ __align__(16) _Float16 hsB[16][1032]; // L2 only: h2(t'-1)
    __shared__ float gs[4][1024];
    __shared__ __align__(16) _Float16 hstage[256];
    int tid = threadIdx.x;
    int w = tid >> 6, l = tid & 63;
    int bid = blockIdx.x;
    int layer = bid >> 6, sb = bid & 63;

    // ---- weight pinning into AGPRs ----
    half8 wA[32];   // L1: Whh1 ; L2: Wih2
    half8 wB[32];   // L2: Whh2
    {
        const _Float16* base = layer ? Wih2 : Whh1;
        const _Float16* wp = base + (size_t)(w * HID + sb * 16 + (l & 15)) * HID + (l >> 4) * 8;
#pragma unroll
        for (int kt = 0; kt < 32; ++kt)
            wA[kt] = to_agpr(*(const half8*)(wp + kt * 32));
        if (layer) {
            const _Float16* wq = Whh2 + (size_t)(w * HID + sb * 16 + (l & 15)) * HID + (l >> 4) * 8;
#pragma unroll
            for (int kt = 0; kt < 32; ++kt)
                wB[kt] = to_agpr(*(const half8*)(wq + kt * 32));
        }
    }
    float bias_v = layer ? b2s[w * HID + sb * 16 + (l & 15)] : 0.f;

    int eb = tid >> 4, ecol = tid & 15;
    int gidx = ((eb >> 2) * 16 + ecol) * 4 + (eb & 3);
    float creg = 0.f;

    const float* xbase = X + (size_t)w * HID + sb * 16 + (l & 15);
    int bq = (l >> 4) * 4;
    f32x4 xreg = {};
    if (!layer) {   // X for t=0
        const float* xp = xbase + (size_t)bq * 4096;
        xreg[0] = xp[0]; xreg[1] = xp[4096];
        xreg[2] = xp[8192]; xreg[3] = xp[12288];
    }

    for (int g = 0; g <= SS; ++g) {
        bool active = layer ? (g >= 1) : (g < SS);
        int t = layer ? g - 1 : g;
        if (active) {
            float xn0, xn1, xn2, xn3;
            if (!layer) {   // X prefetch for t+1
                int tn = (t + 1 < SS) ? t + 1 : SS - 1;
                const float* xp = xbase + (size_t)(tn * 16 + bq) * 4096;
                xn0 = xp[0]; xn1 = xp[4096]; xn2 = xp[8192]; xn3 = xp[12288];
            }

            // ---- stage h vectors -> LDS via MALL-coherent loads ----
            // hsA <- h1buf slot g&1 (both layers); hsB <- h2buf slot (g+1)&1 (L2)
            {
                const _Float16* hbA = h1buf + (g & 1) * 16384 + tid * 8;
                half8 hvA[8], hvB[8];
#pragma unroll
                for (int j = 0; j < 8; ++j) hvA[j] = ldg_h8_cc(hbA + j * 2048);
                if (layer) {
                    const _Float16* hbB = h2buf + ((g + 1) & 1) * 16384 + tid * 8;
#pragma unroll
                    for (int j = 0; j < 8; ++j) hvB[j] = ldg_h8_cc(hbB + j * 2048);
                }
                asm volatile("s_waitcnt vmcnt(0)" ::: "memory");
                __builtin_amdgcn_sched_barrier(0);
#pragma unroll
                for (int j = 0; j < 8; ++j) {
                    int ci = tid + j * 256;
                    int b = (ci >> 1) & 15;
                    int col = ((ci >> 5) << 4) + (ci & 1) * 8;
                    *(half8*)(&hsA[b][col]) = hvA[j];
                    if (layer) *(half8*)(&hsB[b][col]) = hvB[j];
                }
            }
            __syncthreads();

            // ---- MFMAs: 4 chains, chunked fragment loads ----
            f32x4 a0, a1 = {}, a2 = {}, a3 = {};
            if (layer) { a0[0] = bias_v; a0[1] = bias_v; a0[2] = bias_v; a0[3] = bias_v; }
            else a0 = xreg;
            if (layer) {
#pragma unroll
                for (int c = 0; c < 4; ++c) {   // recurrent: h2 x Whh2
                    half8 ha[8];
#pragma unroll
                    for (int j = 0; j < 8; ++j)
                        ha[j] = *(const half8*)(&hsB[l & 15][(c * 8 + j) * 32 + (l >> 4) * 8]);
#pragma unroll
                    for (int j = 0; j < 8; ++j) {
                        f32x4* ac = (j & 3) == 0 ? &a0 : (j & 3) == 1 ? &a1 : (j & 3) == 2 ? &a2 : &a3;
                        *ac = __builtin_amdgcn_mfma_f32_16x16x32_f16(ha[j], wB[c * 8 + j], *ac, 0, 0, 0);
                    }
                }
            }
#pragma unroll
            for (int c = 0; c < 4; ++c) {       // input path: h1 x (Whh1 | Wih2)
                half8 ha[8];
#pragma unroll
                for (int j = 0; j < 8; ++j)
                    ha[j] = *(const half8*)(&hsA[l & 15][(c * 8 + j) * 32 + (l >> 4) * 8]);
#pragma unroll
                for (int j = 0; j < 8; ++j) {
                    f32x4* ac = (j & 3) == 0 ? &a0 : (j & 3) == 1 ? &a1 : (j & 3) == 2 ? &a2 : &a3;
                    *ac = __builtin_amdgcn_mfma_f32_16x16x32_f16(ha[j], wA[c * 8 + j], *ac, 0, 0, 0);
                }
            }
            a0 = (a0 + a1) + (a2 + a3);

            // ---- gate exchange via LDS ----
            *(f32x4*)(&gs[w][l * 4]) = a0;
            __syncthreads();

            // ---- elementwise LSTM cell ----
            float gi = gs[0][gidx], gf = gs[1][gidx], gg = gs[2][gidx], go = gs[3][gidx];
            float cn = sigf(gf) * creg + sigf(gi) * tanh_c(gg);
            float hn = sigf(go) * tanh_c(cn);
            creg = cn;
            hstage[eb * 16 + ecol] = (_Float16)hn;
            if (!layer) { xreg[0] = xn0; xreg[1] = xn1; xreg[2] = xn2; xreg[3] = xn3; }
            __syncthreads();   // hstage ready; gs/hs reads complete

            // ---- publish ----
            if (layer) {
                if (w == 1 && l < 32) {
                    int b = l >> 1, c8 = (l & 1) * 8;
                    *(half8*)(h2seq + (size_t)(t * 16 + b) * HID + sb * 16 + c8) =
                        *(const half8*)(&hstage[l * 8]);
                }
                if (g < SS && w == 0 && l < 32)
                    stg_h8_cc(h2buf + (g & 1) * 16384 + sb * 256 + l * 8,
                              *(const half8*)(&hstage[l * 8]));
            } else {
                if (w == 0 && l < 32)
                    stg_h8_cc(h1buf + ((g + 1) & 1) * 16384 + sb * 256 + l * 8,
                              *(const half8*)(&hstage[l * 8]));
            }
        }

        // ---- unified grid barrier over 128 blocks ----
        if (g < SS) {
            asm volatile("s_waitcnt vmcnt(0)" ::: "memory");  // h stores acked at MALL
            __syncthreads();
            if (tid == 0) stg_u32_cc(flags + (size_t)bid * 16, (unsigned)(g + 1));
            if (tid < RBLK) {
                const unsigned* fp = flags + (size_t)tid * 16;
                while (ldg_u32_cc(fp) <= (unsigned)g) __builtin_amdgcn_s_sleep(1);
            }
            __syncthreads();
        }
    }
}

// ---------------- fused log-softmax (row register-resident) ----------------
__global__ __launch_bounds__(320) void k_lsm(float* __restrict__ logits) {
    int r = blockIdx.x, tid = threadIdx.x;
    float* row = logits + (size_t)r * VOC;
    f32x4 v[25];
    float m = -3.4e38f;
#pragma unroll
    for (int j = 0; j < 25; ++j) {
        v[j] = ((const f32x4*)row)[tid + 320 * j];
        m = fmaxf(fmaxf(fmaxf(m, v[j][0]), fmaxf(v[j][1], v[j][2])), v[j][3]);
    }
#pragma unroll
    for (int off = 1; off < 64; off <<= 1) m = fmaxf(m, __shfl_xor(m, off));
    __shared__ float sm[5], ssum[5];
    int wv = tid >> 6;
    if ((tid & 63) == 0) sm[wv] = m;
    __syncthreads();
    m = fmaxf(fmaxf(fmaxf(sm[0], sm[1]), fmaxf(sm[2], sm[3])), sm[4]);
    float s = 0.f;
#pragma unroll
    for (int j = 0; j < 25; ++j)
        s += (__expf(v[j][0] - m) + __expf(v[j][1] - m)) +
             (__expf(v[j][2] - m) + __expf(v[j][3] - m));
#pragma unroll
    for (int off = 1; off < 64; off <<= 1) s += __shfl_xor(s, off);
    if ((tid & 63) == 0) ssum[wv] = s;
    __syncthreads();
    s = (ssum[0] + ssum[1]) + (ssum[2] + ssum[3]) + ssum[4];
    float lse = m + __logf(s);
#pragma unroll
    for (int j = 0; j < 25; ++j) {
        f32x4 o = v[j];
        o[0] -= lse; o[1] -= lse; o[2] -= lse; o[3] -= lse;
        ((f32x4*)row)[tid + 320 * j] = o;
    }
}

// ---------------- launch ----------------
extern "C" void kernel_launch(void* const* d_in, const int* in_sizes, int n_in,
                              void* d_out, int out_size, void* d_ws, size_t ws_size,
                              hipStream_t stream) {
    const int*   tok   = (const int*)d_in[0];
    const float* emb   = (const float*)d_in[1];
    const float* W_ih1 = (const float*)d_in[2];
    const float* W_hh1 = (const float*)d_in[3];
    const float* b_ih1 = (const float*)d_in[4];
    const float* b_hh1 = (const float*)d_in[5];
    const float* W_ih2 = (const float*)d_in[6];
    const float* W_hh2 = (const float*)d_in[7];
    const float* b_ih2 = (const float*)d_in[8];
    const float* b_hh2 = (const float*)d_in[9];
    const float* W_log = (const float*)d_in[10];
    const float* b_log = (const float*)d_in[11];
    float* out = (float*)d_out;

    char* w = (char*)d_ws;
    auto alloc = [&](size_t bytes) {
        char* p = w;
        w += (bytes + 255) & ~(size_t)255;
        return p;
    };
    _Float16* Wih1h = (_Float16*)alloc((size_t)4096 * 512 * 2);
    _Float16* Whh1h = (_Float16*)alloc((size_t)4096 * 1024 * 2);
    _Float16* Wih2h = (_Float16*)alloc((size_t)4096 * 1024 * 2);
    _Float16* Whh2h = (_Float16*)alloc((size_t)4096 * 1024 * 2);
    _Float16* Wlogh = (_Float16*)alloc((size_t)VOC * 1024 * 2);
    _Float16* Abuf  = (_Float16*)alloc((size_t)4096 * 512 * 2);
    float* X        = (float*)alloc((size_t)4096 * 4096 * 4);
    _Float16* h2seq = (_Float16*)alloc((size_t)4096 * 1024 * 2);
    float* b1s      = (float*)alloc(4096 * 4);
    float* b2s      = (float*)alloc(4096 * 4);
    _Float16* h1buf = (_Float16*)alloc((size_t)2 * 16384 * 2);  // 64 KB
    _Float16* h2buf = (_Float16*)alloc((size_t)2 * 16384 * 2);  // 64 KB
    unsigned* flags = (unsigned*)alloc(RBLK * 64);              // 8 KB
    // h1buf, h2buf, flags are contiguous (each 256B-aligned size): zero once
    k_zero<<<72, 256, 0, stream>>>((float*)h1buf, (65536 + 65536 + 8192) / 4);

    // weight conversions f32 -> f16 (idempotent)
    k_f32_to_f16<<<2048, 256, 0, stream>>>(W_ih1, Wih1h, 4096 * 512 / 4);
    k_f32_to_f16<<<2048, 256, 0, stream>>>(W_hh1, Whh1h, 4096 * 1024 / 4);
    k_f32_to_f16<<<2048, 256, 0, stream>>>(W_ih2, Wih2h, 4096 * 1024 / 4);
    k_f32_to_f16<<<2048, 256, 0, stream>>>(W_hh2, Whh2h, 4096 * 1024 / 4);
    k_f32_to_f16<<<2048, 256, 0, stream>>>(W_log, Wlogh, VOC * 1024 / 4);
    k_bias<<<16, 256, 0, stream>>>(b_ih1, b_hh1, b_ih2, b_hh2, b1s, b2s);

    // X1 = embed @ W_ih1^T + (b_ih1 + b_hh1)
    k_embed<<<2048, 256, 0, stream>>>(tok, emb, Abuf);
    k_gemm_bt<<<dim3(32, 32), 256, 0, stream>>>(Abuf, Wih1h, b1s, X, 4096, 4096, 512, 0);

    // pipelined 2-layer recurrence (persistent, 128 blocks)
    k_rnn<<<RBLK, 256, 0, stream>>>(X, Whh1h, Wih2h, Whh2h, b2s,
                                    h1buf, h2buf, h2seq, flags);

    // logits = h2_seq @ W_log^T + b_log, scattered to [b][t][v]
    k_gemm_bt<<<dim3(VOC / 128, 32), 256, 0, stream>>>(h2seq, Wlogh, b_log, out,
                                                       4096, VOC, 1024, 1);

    // fused log-softmax in place
    k_lsm<<<4096, 320, 0, stream>>>(out);
}